// Round 8
// baseline (164.376 us; speedup 1.0000x reference)
//
#include <hip/hip_runtime.h>

#define NHEADS 16
#define HDIM   64
#define NFEAT  32
#define PDIM   16
#define NQUAD  2
#define GB     16     // b's per wave: grid 1024 = 4 blocks/CU, ALL resident (no churn)
#define WAVES_PB 4

typedef float f32x4 __attribute__((ext_vector_type(4)));

// out[b, r, h, p, m] flat = b*16384 + r*8192 + h*512 + p*32 + m
__global__ __launch_bounds__(256, 4)
void slay_kernel(const float* __restrict__ x,
                 const float* __restrict__ omega,
                 const float* __restrict__ anchors,
                 const float* __restrict__ qn,
                 const float* __restrict__ qw,
                 float* __restrict__ out)
{
    __shared__ __align__(16) float s_xn  [WAVES_PB][64];
    __shared__ __align__(16) float s_prf [2][WAVES_PB][64];
    __shared__ __align__(16) float s_poly[2][WAVES_PB][16];

    const int tid  = threadIdx.x;
    const int wv   = tid >> 6;
    const int lane = tid & 63;
    const int h    = blockIdx.x & 15;
    const int b0   = ((blockIdx.x >> 4) * WAVES_PB + wv) * GB;

    const int r = lane >> 5;   // quadrature node
    const int m = lane & 31;   // feature index
    const int p = lane & 15;   // poly index
    const int g = lane >> 4;   // d-group for poly partial dot

    const float sR     = fmaxf(qn[r], 1e-6f);
    const float sq2s   = sqrtf(2.0f * sR);
    const float scaleR = sqrtf(fmaxf(qw[r], 1e-6f)) / sqrtf(32.0f + 1e-6f);

    float om[64];
    {
        const float* oc = omega + ((size_t)(r * NHEADS + h) * HDIM) * NFEAT + m;
        #pragma unroll
        for (int d = 0; d < 64; ++d) om[d] = oc[(size_t)d * NFEAT];
    }
    float an[16];
    {
        const float* ac = anchors + p * HDIM + g * 16;
        #pragma unroll
        for (int dd = 0; dd < 16; ++dd) an[dd] = ac[dd];
    }

    const float* xb = x + (size_t)b0 * (NHEADS * HDIM) + h * HDIM + lane;
    float xcur = xb[0];
    float* const obase = out + (size_t)b0 * (NQUAD * NHEADS * PDIM * NFEAT)
                             + (size_t)h * (PDIM * NFEAT);

// One task. PH selects LDS buffer; W0..W3 are the payload regs for this phase —
// two distinct sets alternate across tasks so task i's stores stay in flight
// through ALL of task i+1's compute (no vmcnt wait until the set is reused).
#define SLAY_STEP(BB, PH, W0, W1, W2, W3)                                        \
    {                                                                            \
        const int bnx = ((BB) + 1 < GB) ? (BB) + 1 : (GB - 1);                   \
        const float xnext = xb[(size_t)bnx * (NHEADS * HDIM)];                   \
        float ss = xcur * xcur;                                                  \
        ss += __shfl_xor(ss, 32, 64);  ss += __shfl_xor(ss, 16, 64);             \
        ss += __shfl_xor(ss,  8, 64);  ss += __shfl_xor(ss,  4, 64);             \
        ss += __shfl_xor(ss,  2, 64);  ss += __shfl_xor(ss,  1, 64);             \
        const float xn = xcur / fmaxf(sqrtf(ss), 1e-4f);                         \
        __builtin_amdgcn_wave_barrier();                                         \
        s_xn[wv][lane] = xn;                                                     \
        __builtin_amdgcn_wave_barrier();                                         \
        float a0 = 0.f, a1 = 0.f, a2 = 0.f, a3 = 0.f;                            \
        _Pragma("unroll")                                                        \
        for (int d = 0; d < 64; d += 4) {                                        \
            const float s0 = __uint_as_float(__builtin_amdgcn_readlane(__float_as_uint(xn), d + 0)); \
            const float s1 = __uint_as_float(__builtin_amdgcn_readlane(__float_as_uint(xn), d + 1)); \
            const float s2 = __uint_as_float(__builtin_amdgcn_readlane(__float_as_uint(xn), d + 2)); \
            const float s3 = __uint_as_float(__builtin_amdgcn_readlane(__float_as_uint(xn), d + 3)); \
            a0 = fmaf(s0, om[d + 0], a0);  a1 = fmaf(s1, om[d + 1], a1);         \
            a2 = fmaf(s2, om[d + 2], a2);  a3 = fmaf(s3, om[d + 3], a3);         \
        }                                                                        \
        const float accR = (a0 + a1) + (a2 + a3);                                \
        float p0 = 0.f, p1 = 0.f, p2 = 0.f, p3 = 0.f;                            \
        _Pragma("unroll")                                                        \
        for (int q4 = 0; q4 < 4; ++q4) {                                         \
            const f32x4 xq = *(const f32x4*)&s_xn[wv][g * 16 + q4 * 4];          \
            p0 = fmaf(xq.x, an[q4 * 4 + 0], p0);                                 \
            p1 = fmaf(xq.y, an[q4 * 4 + 1], p1);                                 \
            p2 = fmaf(xq.z, an[q4 * 4 + 2], p2);                                 \
            p3 = fmaf(xq.w, an[q4 * 4 + 3], p3);                                 \
        }                                                                        \
        float accP = (p0 + p1) + (p2 + p3);                                      \
        accP += __shfl_xor(accP, 16, 64);                                        \
        accP += __shfl_xor(accP, 32, 64);                                        \
        const float arg  = fminf(fmaxf(accR * sq2s - sR, -20.f), 20.f);          \
        const float prf  = expf(arg) * scaleR;                                   \
        const float pc   = fminf(fmaxf(accP, -1.f), 1.f);                        \
        const float poly = pc * pc * 0.25f;                                      \
        __builtin_amdgcn_wave_barrier();                                         \
        s_prf[PH][wv][lane] = prf;                                               \
        if (lane < 16) s_poly[PH][wv][lane] = poly;                              \
        __builtin_amdgcn_wave_barrier();                                         \
        float* ob = obase + (size_t)(BB) * (NQUAD * NHEADS * PDIM * NFEAT);      \
        const float pfA = s_poly[PH][wv][lane >> 3];                             \
        const float pfB = s_poly[PH][wv][8 + (lane >> 3)];                       \
        const f32x4 prA = *(const f32x4*)&s_prf[PH][wv][(lane & 7) * 4];         \
        const f32x4 prB = *(const f32x4*)&s_prf[PH][wv][32 + (lane & 7) * 4];    \
        W0 = pfA * prA;  W1 = pfB * prA;  W2 = pfA * prB;  W3 = pfB * prB;       \
        *(f32x4*)(ob +    0 + lane * 4) = W0;                                    \
        *(f32x4*)(ob +  256 + lane * 4) = W1;                                    \
        *(f32x4*)(ob + 8192 + lane * 4) = W2;                                    \
        *(f32x4*)(ob + 8448 + lane * 4) = W3;                                    \
        xcur = xnext;                                                            \
    }

    f32x4 vA0, vA1, vA2, vA3, vB0, vB1, vB2, vB3;
    for (int bb = 0; bb < GB; bb += 2) {
        SLAY_STEP(bb,     0, vA0, vA1, vA2, vA3);
        SLAY_STEP(bb + 1, 1, vB0, vB1, vB2, vB3);
    }
#undef SLAY_STEP
}

extern "C" void kernel_launch(void* const* d_in, const int* in_sizes, int n_in,
                              void* d_out, int out_size, void* d_ws, size_t ws_size,
                              hipStream_t stream)
{
    const float* x       = (const float*)d_in[0];
    const float* omega   = (const float*)d_in[1];
    const float* anchors = (const float*)d_in[2];
    const float* qn      = (const float*)d_in[3];
    const float* qw      = (const float*)d_in[4];
    float* out = (float*)d_out;

    const int Bsz = in_sizes[0] / (NHEADS * HDIM);          // 4096
    dim3 grid((Bsz / (WAVES_PB * GB)) * NHEADS);            // 64 * 16 = 1024
    slay_kernel<<<grid, 256, 0, stream>>>(x, omega, anchors, qn, qw, out);
}

// Round 9
// 62.647 us; speedup vs baseline: 2.6238x; 2.6238x over previous
//
#include <hip/hip_runtime.h>

#define NHEADS 16
#define HDIM   64
#define NFEAT  32
#define PDIM   16
#define NQUAD  2
#define GB     8      // b's processed per wave
#define WAVES_PB 4    // waves per 256-thread block

typedef float f32x4 __attribute__((ext_vector_type(4)));

// out[b, r, h, p, m] flat = b*16384 + r*8192 + h*512 + p*32 + m
// launch_bounds (256,3): VGPR cap ~170 so om[64]+an[16]+xvv[8]+temps fit with
// ZERO scratch spill. Spill reloads share the vmcnt FIFO with output stores
// (R8 evidence: VGPR=64, FETCH=254MB) and lock compute to store drain.
__global__ __launch_bounds__(256, 3)
void slay_kernel(const float* __restrict__ x,
                 const float* __restrict__ omega,
                 const float* __restrict__ anchors,
                 const float* __restrict__ qn,
                 const float* __restrict__ qw,
                 float* __restrict__ out)
{
    // all buffers are PER-WAVE: no __syncthreads needed, wave_barrier only
    __shared__ __align__(16) float s_xn [WAVES_PB][64];
    __shared__ __align__(16) float s_prf[WAVES_PB][64];
    __shared__ __align__(16) float s_poly[WAVES_PB][16];

    const int tid  = threadIdx.x;
    const int wv   = tid >> 6;
    const int lane = tid & 63;
    const int h    = blockIdx.x & 15;
    const int b0   = ((blockIdx.x >> 4) * WAVES_PB + wv) * GB;

    const int r = lane >> 5;   // quadrature node index
    const int m = lane & 31;   // feature index
    const int p = lane & 15;   // poly index (4x redundant)
    const int g = lane >> 4;   // d-group for poly partial dot

    const float sR     = fmaxf(qn[r], 1e-6f);
    const float sq2s   = sqrtf(2.0f * sR);
    const float scaleR = sqrtf(fmaxf(qw[r], 1e-6f)) / sqrtf(32.0f + 1e-6f);

    // preload omega column om[d] = omega[r][h][d][m]
    float om[64];
    {
        const float* oc = omega + ((size_t)(r * NHEADS + h) * HDIM) * NFEAT + m;
        #pragma unroll
        for (int d = 0; d < 64; ++d) om[d] = oc[(size_t)d * NFEAT];
    }
    // anchors slice: an[dd] = anchors[p][g*16 + dd]  (only 16 regs)
    float an[16];
    {
        const float* ac = anchors + p * HDIM + g * 16;
        #pragma unroll
        for (int dd = 0; dd < 16; ++dd) an[dd] = ac[dd];
    }

    // hoist all GB x loads (independent; overlap their latency)
    float xvv[GB];
    {
        const float* xb = x + (size_t)b0 * (NHEADS * HDIM) + h * HDIM + lane;
        #pragma unroll
        for (int bb = 0; bb < GB; ++bb) xvv[bb] = xb[(size_t)bb * (NHEADS * HDIM)];
    }

    #pragma unroll
    for (int bb = 0; bb < GB; ++bb) {
        const int b = b0 + bb;

        // ---- normalize x[b, h, :] (lane = d) ----
        float ss = xvv[bb] * xvv[bb];
        #pragma unroll
        for (int off = 32; off > 0; off >>= 1) ss += __shfl_xor(ss, off, 64);
        const float xn = xvv[bb] / fmaxf(sqrtf(ss), 1e-4f);

        // stage xn per-wave for the poly path (compile-time fences only)
        __builtin_amdgcn_wave_barrier();
        s_xn[wv][lane] = xn;
        __builtin_amdgcn_wave_barrier();

        // ---- prf dot: readlane broadcast, 4 independent accum chains ----
        float a0 = 0.f, a1 = 0.f, a2 = 0.f, a3 = 0.f;
        #pragma unroll
        for (int d = 0; d < 64; d += 4) {
            const float s0 = __uint_as_float(__builtin_amdgcn_readlane(__float_as_uint(xn), d + 0));
            const float s1 = __uint_as_float(__builtin_amdgcn_readlane(__float_as_uint(xn), d + 1));
            const float s2 = __uint_as_float(__builtin_amdgcn_readlane(__float_as_uint(xn), d + 2));
            const float s3 = __uint_as_float(__builtin_amdgcn_readlane(__float_as_uint(xn), d + 3));
            a0 = fmaf(s0, om[d + 0], a0);
            a1 = fmaf(s1, om[d + 1], a1);
            a2 = fmaf(s2, om[d + 2], a2);
            a3 = fmaf(s3, om[d + 3], a3);
        }
        const float accR = (a0 + a1) + (a2 + a3);

        // ---- poly dot: this lane's 16-d slice from LDS, group-reduce ----
        float p0 = 0.f, p1 = 0.f, p2 = 0.f, p3 = 0.f;
        #pragma unroll
        for (int q4 = 0; q4 < 4; ++q4) {
            const f32x4 xq = *(const f32x4*)&s_xn[wv][g * 16 + q4 * 4];
            p0 = fmaf(xq.x, an[q4 * 4 + 0], p0);
            p1 = fmaf(xq.y, an[q4 * 4 + 1], p1);
            p2 = fmaf(xq.z, an[q4 * 4 + 2], p2);
            p3 = fmaf(xq.w, an[q4 * 4 + 3], p3);
        }
        float accP = (p0 + p1) + (p2 + p3);
        accP += __shfl_xor(accP, 16, 64);   // combine the 4 d-groups
        accP += __shfl_xor(accP, 32, 64);

        // ---- feature epilogues ----
        const float arg  = fminf(fmaxf(accR * sq2s - sR, -20.f), 20.f);
        const float prf  = expf(arg) * scaleR;
        const float pc   = fminf(fmaxf(accP, -1.f), 1.f);
        const float poly = pc * pc * 0.25f;

        // ---- stage per-wave, expand + write (no block barrier!) ----
        __builtin_amdgcn_wave_barrier();
        s_prf[wv][lane] = prf;
        if (lane < 16) s_poly[wv][lane] = poly;
        __builtin_amdgcn_wave_barrier();

        float* ob = out + (size_t)b * (NQUAD * NHEADS * PDIM * NFEAT)
                        + (size_t)h * (PDIM * NFEAT);
        #pragma unroll
        for (int i4 = 0; i4 < 4; ++i4) {
            const int rr = i4 >> 1;
            const int pp = (i4 * 8 + (lane >> 3)) & 15;
            const float pf = s_poly[wv][pp];
            const f32x4 pr = *(const f32x4*)&s_prf[wv][rr * 32 + (lane & 7) * 4];
            f32x4 v;
            v.x = pf * pr.x; v.y = pf * pr.y; v.z = pf * pr.z; v.w = pf * pr.w;
            *(f32x4*)(ob + (size_t)rr * (NHEADS * PDIM * NFEAT)
                         + (i4 & 1) * 256 + lane * 4) = v;
        }
    }
}

extern "C" void kernel_launch(void* const* d_in, const int* in_sizes, int n_in,
                              void* d_out, int out_size, void* d_ws, size_t ws_size,
                              hipStream_t stream)
{
    const float* x       = (const float*)d_in[0];
    const float* omega   = (const float*)d_in[1];
    const float* anchors = (const float*)d_in[2];
    const float* qn      = (const float*)d_in[3];
    const float* qw      = (const float*)d_in[4];
    float* out = (float*)d_out;

    const int Bsz = in_sizes[0] / (NHEADS * HDIM);          // 4096
    dim3 grid((Bsz / (WAVES_PB * GB)) * NHEADS);            // 128 * 16 = 2048
    slay_kernel<<<grid, 256, 0, stream>>>(x, omega, anchors, qn, qw, out);
}